// Round 13
// baseline (205.653 us; speedup 1.0000x reference)
//
#include <hip/hip_runtime.h>

#define NN 50000
#define NE 800000
#define NF 128
#define NH 64
#define BN_EPS 1e-5f
#define NB 196       // ceil(NN/256) coarse buckets (256 nodes each)
#define EPB 2048     // edges per k_part block
#define CAP 5120     // fixed per-bucket capacity (mean 4082, +16 sigma)
#define NCOPY 16
#define SEG (NCOPY * 128)
#define PL ((size_t)NN * 32)  // plane stride in ushorts

typedef __bf16 bf16x8 __attribute__((ext_vector_type(8)));
typedef float f32x4 __attribute__((ext_vector_type(4)));
#define MFMA __builtin_amdgcn_mfma_f32_16x16x32_bf16

__device__ inline unsigned short bf_hi(float f) {
  unsigned u = __float_as_uint(f);
  unsigned r = u + 0x7FFFu + ((u >> 16) & 1u);
  return (unsigned short)(r >> 16);
}
__device__ inline float bf_to_f(unsigned short s) {
  return __uint_as_float(((unsigned)s) << 16);
}
__device__ inline float bf_lo_f(unsigned u) { return __uint_as_float(u << 16); }
__device__ inline float bf_hi_f(unsigned u) { return __uint_as_float(u & 0xFFFF0000u); }

union BF8 { bf16x8 v; unsigned short s[8]; };

// Build hi/lo bf16x8 fragments from 8 consecutive fp32.
__device__ inline void make_ab(const float* p, bool valid, bf16x8& hi, bf16x8& lo) {
  BF8 H, L;
  if (valid) {
    float4 f0 = *(const float4*)p;
    float4 f1 = *(const float4*)(p + 4);
    float ff[8] = {f0.x, f0.y, f0.z, f0.w, f1.x, f1.y, f1.z, f1.w};
#pragma unroll
    for (int e = 0; e < 8; ++e) {
      unsigned short h = bf_hi(ff[e]);
      H.s[e] = h;
      L.s[e] = bf_hi(ff[e] - bf_to_f(h));
    }
  } else {
#pragma unroll
    for (int e = 0; e < 8; ++e) { H.s[e] = 0; L.s[e] = 0; }
  }
  hi = H.v; lo = L.v;
}

// fragment-layout offset for a [K][64] matrix
__device__ inline int frag_off(int k, int c) {
  return ((k >> 5) * 4 + (c >> 4)) * 512 + (((k >> 3) & 3) * 16 + (c & 15)) * 8 + (k & 7);
}

// ---- prep: zero counters/partials + convert all weights to hi/lo fragment planes ----

__global__ __launch_bounds__(256) void k_prep(const float* __restrict__ Wt,
                                              const float* __restrict__ Ws1,
                                              const float* __restrict__ Ws2,
                                              unsigned short* __restrict__ wp,
                                              int* __restrict__ ccur,
                                              float* __restrict__ partials) {
  int idx = blockIdx.x * 256 + threadIdx.x;  // 0..32767
  if (idx < NB) ccur[idx] = 0;
  if (idx < 4 * SEG) partials[idx] = 0.f;
  if (idx < 8192) {
    int k = idx >> 6, c = idx & 63;
    float f = Wt[idx];
    int off = frag_off(k, c);
    unsigned short h = bf_hi(f);
    wp[off] = h;
    wp[8192 + off] = bf_hi(f - bf_to_f(h));
  } else {
    int rem = idx - 8192;       // 0..24575
    int l = rem >> 13;          // layer 0..2
    int r2 = rem & 8191;
    int mat = r2 >> 12;         // 0=W1, 1=W2
    int e = r2 & 4095;
    int k = e >> 6, c = e & 63;
    float f = (mat ? Ws2 : Ws1)[l * 4096 + e];
    int off = frag_off(k, c);
    unsigned short* base = wp + 16384 + l * 16384 + mat * 8192;
    unsigned short h = bf_hi(f);
    base[off] = h;
    base[off + 4096] = bf_hi(f - bf_to_f(h));
  }
}

// -------- phase 1: partition packed records into FIXED-STRIDE coarse buckets --------

__global__ __launch_bounds__(256) void k_part(const int* __restrict__ src,
                                              const int* __restrict__ dst,
                                              int* __restrict__ ccur,
                                              int* __restrict__ pairs) {
  __shared__ int lh[NB];
  __shared__ int gb[NB];
  __shared__ int lc[NB];
  __shared__ int ls[256];
  __shared__ int lp[EPB];
  __shared__ int gx[EPB];
  int t = threadIdx.x;
  for (int i = t; i < NB; i += 256) lh[i] = 0;
  __syncthreads();
  int e0 = blockIdx.x * EPB;
  int nloc = NE - e0; if (nloc > EPB) nloc = EPB;
#pragma unroll
  for (int i = 0; i < EPB / 256; ++i) {
    int e = e0 + i * 256 + t;
    if (e < NE) atomicAdd(&lh[dst[e] >> 8], 1);
  }
  __syncthreads();
  int v = (t < NB) ? lh[t] : 0;
  ls[t] = v;
  __syncthreads();
  for (int off = 1; off < 256; off <<= 1) {
    int u = (t >= off) ? ls[t - off] : 0;
    __syncthreads();
    ls[t] += u;
    __syncthreads();
  }
  int lbase = ls[t] - v;
  int gbase = 0;
  if (t < NB && v > 0) gbase = t * CAP + atomicAdd(&ccur[t], v);
  if (t < NB) { lh[t] = lbase; gb[t] = gbase; lc[t] = 0; }
  __syncthreads();
#pragma unroll
  for (int i = 0; i < EPB / 256; ++i) {
    int e = e0 + i * 256 + t;
    if (e < NE) {
      int d = dst[e], s = src[e];
      int b = d >> 8;
      int lpos = lh[b] + atomicAdd(&lc[b], 1);
      lp[lpos] = ((d & 255) << 16) | s;
      gx[lpos] = gb[b] - lh[b];
    }
  }
  __syncthreads();
  for (int i = t; i < nloc; i += 256) pairs[gx[i] + i] = lp[i];
}

// ---- phase 2: exact sort within bucket -> rowptr + ebuf(ushort) ----

__global__ __launch_bounds__(256) void k_sub(const int* __restrict__ pairs,
                                             const int* __restrict__ ccur,
                                             int* __restrict__ rowptr,
                                             unsigned short* __restrict__ ebuf) {
  __shared__ int lh[256];
  __shared__ int lsc[256];
  __shared__ int lc2[256];
  __shared__ unsigned short ssrc[CAP];
  int t = threadIdx.x;
  int b = blockIdx.x;
  int gv = (t < NB) ? ccur[t] : 0;
  lsc[t] = gv;
  __syncthreads();
  for (int off = 1; off < 256; off <<= 1) {
    int u = (t >= off) ? lsc[t - off] : 0;
    __syncthreads();
    lsc[t] += u;
    __syncthreads();
  }
  int beg = (b == 0) ? 0 : lsc[b - 1];
  int n = lsc[b] - beg;
  __syncthreads();
  const int* bp = pairs + b * CAP;
  lh[t] = 0;
  lc2[t] = 0;
  __syncthreads();
  for (int i = t; i < n; i += 256) atomicAdd(&lh[(bp[i] >> 16) & 255], 1);
  __syncthreads();
  int v = lh[t];
  lsc[t] = v;
  __syncthreads();
  for (int off = 1; off < 256; off <<= 1) {
    int u = (t >= off) ? lsc[t - off] : 0;
    __syncthreads();
    lsc[t] += u;
    __syncthreads();
  }
  int excl = lsc[t] - v;
  int node = b * 256 + t;
  if (node <= NN) rowptr[node] = beg + excl;
  for (int i = t; i < n; i += 256) {
    int p = bp[i];
    int ln = (p >> 16) & 255;
    int lpos = (lsc[ln] - lh[ln]) + atomicAdd(&lc2[ln], 1);
    if (lpos < CAP) ssrc[lpos] = (unsigned short)(p & 0xFFFF);
  }
  __syncthreads();
  for (int i = t; i < n; i += 256) ebuf[beg + i] = ssrc[i];
}

// ------- input transform (MFMA); output zb in 2-plane [2][NN][32] layout -------

__global__ __launch_bounds__(256) void k_in(const float* __restrict__ x,
                                            const unsigned short* __restrict__ wth,
                                            const unsigned short* __restrict__ wtl,
                                            const float* __restrict__ bt,
                                            unsigned short* __restrict__ zb,
                                            float* __restrict__ part_out) {
  __shared__ unsigned short lwh[8192], lwl[8192];  // 32 KB
  int t = threadIdx.x;
  {
    const uint4* gh = (const uint4*)wth;
    const uint4* gl = (const uint4*)wtl;
    uint4* dh = (uint4*)lwh;
    uint4* dl = (uint4*)lwl;
#pragma unroll
    for (int i = 0; i < 4; ++i) {
      dh[t + i * 256] = gh[t + i * 256];
      dl[t + i * 256] = gl[t + i * 256];
    }
  }
  int wv = t >> 6, lane = t & 63;
  int c15 = lane & 15, kg = lane >> 4;
  int n0 = blockIdx.x * 64 + wv * 16;
  int arow = n0 + c15;
  bool valid = arow < NN;

  bf16x8 ah[4], al[4];
  const float* ap = x + (size_t)(valid ? arow : 0) * NF + kg * 8;
#pragma unroll
  for (int ks = 0; ks < 4; ++ks) make_ab(ap + ks * 32, valid, ah[ks], al[ks]);
  __syncthreads();

  const bf16x8* bh = (const bf16x8*)lwh;
  const bf16x8* bl = (const bf16x8*)lwl;
  float sAcc[4], ssAcc[4];
#pragma unroll
  for (int ct = 0; ct < 4; ++ct) {
    f32x4 acc = {0.f, 0.f, 0.f, 0.f};
#pragma unroll
    for (int ks = 0; ks < 4; ++ks) {
      bf16x8 wbh = bh[(ks * 4 + ct) * 64 + lane];
      bf16x8 wbl = bl[(ks * 4 + ct) * 64 + lane];
      acc = MFMA(al[ks], wbh, acc, 0, 0, 0);
      acc = MFMA(ah[ks], wbl, acc, 0, 0, 0);
      acc = MFMA(ah[ks], wbh, acc, 0, 0, 0);
    }
    float b = bt[ct * 16 + c15];
    float s = 0.f, ss = 0.f;
    unsigned short* zp = zb + (size_t)(ct >> 1) * PL + (ct & 1) * 16 + c15;
#pragma unroll
    for (int g = 0; g < 4; ++g) {
      int row = n0 + kg * 4 + g;
      float v = acc[g] + b;
      if (row < NN) {
        zp[(size_t)row * 32] = bf_hi(v);
        s += v;
        ss += v * v;
      }
    }
    sAcc[ct] = s;
    ssAcc[ct] = ss;
  }
#pragma unroll
  for (int ct = 0; ct < 4; ++ct) {
    float s = sAcc[ct];
    s += __shfl_xor(s, 16); s += __shfl_xor(s, 32);
    float ss = ssAcc[ct];
    ss += __shfl_xor(ss, 16); ss += __shfl_xor(ss, 32);
    if (kg == 0) {
      int cp = ((blockIdx.x * 4 + wv) & (NCOPY - 1)) * 128;
      atomicAdd(&part_out[cp + ct * 16 + c15], s);
      atomicAdd(&part_out[cp + 64 + ct * 16 + c15], ss);
    }
  }
}

// ======== fused layer: per-plane gather+BN -> LDS m tile -> MFMA MLP ========
// zb/rb in [2][NN][32] plane layout; gather walks edges once per 3.2MB plane (L2-resident)

__global__ __launch_bounds__(1024) void k_layer(const unsigned short* __restrict__ zb,
                                                const unsigned short* __restrict__ ebuf,
                                                const int* __restrict__ rowptr,
                                                const float* __restrict__ part_in,
                                                const float* __restrict__ gamma,
                                                const float* __restrict__ beta,
                                                const unsigned short* __restrict__ wl,
                                                unsigned short* __restrict__ rb,
                                                float* __restrict__ part_out) {
  __shared__ unsigned short lw[16384];       // W1h|W1l|W2h|W2l (32 KB)
  __shared__ float mt[64][68];               // m tile fp32; reused for stats
  __shared__ unsigned short tt[2][64][72];   // t tile hi/lo
  __shared__ float sc[64], sh[64];
  int t = threadIdx.x;
  {  // stage weights (plain vector copy)
    const uint4* g = (const uint4*)wl;
    uint4* d = (uint4*)lw;
    d[t] = g[t];
    d[t + 1024] = g[t + 1024];
  }
  if (t < 64) {
    float s = 0.f, ss = 0.f;
#pragma unroll
    for (int c = 0; c < NCOPY; ++c) { s += part_in[c * 128 + t]; ss += part_in[c * 128 + 64 + t]; }
    float invn = 1.f / (float)NN;
    float mu = s * invn;
    float var = fmaxf(ss * invn - mu * mu, 0.f);
    float inv = rsqrtf(var + BN_EPS);
    float scale = gamma[t] * inv;
    sc[t] = scale;
    sh[t] = beta[t] - mu * scale;
  }
  __syncthreads();  // B0: weights + sc/sh ready

  int wv = t >> 6, lane = t & 63;
  int slot = lane >> 3;   // edge slot 0..7
  int cg = lane & 7;      // channel group within plane (4 ch each)
  int nbase = blockIdx.x * 64;

  // ---- phase 1: per-plane gather, 8 edges/wave-iter ----
#pragma unroll
  for (int p = 0; p < 2; ++p) {
    const unsigned short* zp = zb + (size_t)p * PL;
    int cbase = p * 32 + cg * 4;
    for (int i = 0; i < 4; ++i) {
      int nl = wv * 4 + i;
      int node = nbase + nl;
      if (node >= NN) {
        if (slot == 0) *(float4*)&mt[nl][cbase] = make_float4(0.f, 0.f, 0.f, 0.f);
        continue;  // wave-uniform
      }
      int beg = rowptr[node], end = rowptr[node + 1];
      float a0 = 0.f, a1 = 0.f, a2 = 0.f, a3 = 0.f;
      if (slot == 0) {  // self term (bf16)
        uint2 u = *(const uint2*)(zp + (size_t)node * 32 + cg * 4);
        a0 = bf_lo_f(u.x); a1 = bf_hi_f(u.x); a2 = bf_lo_f(u.y); a3 = bf_hi_f(u.y);
      }
      int j = beg + slot;
      for (; j + 8 < end; j += 16) {  // 16 edges/wave-iter, 2 rows in flight per lane
        int s0 = ebuf[j];
        int s1 = ebuf[j + 8];
        uint2 u0 = *(const uint2*)(zp + (size_t)s0 * 32 + cg * 4);
        uint2 u1 = *(const uint2*)(zp + (size_t)s1 * 32 + cg * 4);
        a0 += bf_lo_f(u0.x) + bf_lo_f(u1.x);
        a1 += bf_hi_f(u0.x) + bf_hi_f(u1.x);
        a2 += bf_lo_f(u0.y) + bf_lo_f(u1.y);
        a3 += bf_hi_f(u0.y) + bf_hi_f(u1.y);
      }
      for (; j < end; j += 8) {
        int s0 = ebuf[j];
        uint2 u0 = *(const uint2*)(zp + (size_t)s0 * 32 + cg * 4);
        a0 += bf_lo_f(u0.x);
        a1 += bf_hi_f(u0.x);
        a2 += bf_lo_f(u0.y);
        a3 += bf_hi_f(u0.y);
      }
      a0 += __shfl_xor(a0, 8); a0 += __shfl_xor(a0, 16); a0 += __shfl_xor(a0, 32);
      a1 += __shfl_xor(a1, 8); a1 += __shfl_xor(a1, 16); a1 += __shfl_xor(a1, 32);
      a2 += __shfl_xor(a2, 8); a2 += __shfl_xor(a2, 16); a2 += __shfl_xor(a2, 32);
      a3 += __shfl_xor(a3, 8); a3 += __shfl_xor(a3, 16); a3 += __shfl_xor(a3, 32);
      if (slot == 0) {
        float deg1 = (float)(end - beg + 1);
        float4 o;
        o.x = sc[cbase + 0] * a0 + deg1 * sh[cbase + 0];
        o.y = sc[cbase + 1] * a1 + deg1 * sh[cbase + 1];
        o.z = sc[cbase + 2] * a2 + deg1 * sh[cbase + 2];
        o.w = sc[cbase + 3] * a3 + deg1 * sh[cbase + 3];
        *(float4*)&mt[nl][cbase] = o;
      }
    }
  }
  __syncthreads();  // B1: m tile complete

  // ---- phase 2: GEMM1 (16 waves = 4 row-blocks x 4 col-tiles) ----
  int rw = (wv >> 2) * 16;  // row offset of this wave's 16x16 tile
  int ct = wv & 3;          // col tile
  int c15 = lane & 15, kg = lane >> 4;

  bf16x8 ah[2], al[2];
#pragma unroll
  for (int ks = 0; ks < 2; ++ks) make_ab(&mt[rw + c15][ks * 32 + kg * 8], true, ah[ks], al[ks]);

  const bf16x8* b1h = (const bf16x8*)lw;
  const bf16x8* b1l = (const bf16x8*)(lw + 4096);
  {
    f32x4 acc = {0.f, 0.f, 0.f, 0.f};
#pragma unroll
    for (int ks = 0; ks < 2; ++ks) {
      bf16x8 wbh = b1h[(ks * 4 + ct) * 64 + lane];
      bf16x8 wbl = b1l[(ks * 4 + ct) * 64 + lane];
      acc = MFMA(al[ks], wbh, acc, 0, 0, 0);
      acc = MFMA(ah[ks], wbl, acc, 0, 0, 0);
      acc = MFMA(ah[ks], wbh, acc, 0, 0, 0);
    }
#pragma unroll
    for (int g = 0; g < 4; ++g) {
      float v = fmaxf(acc[g], 0.f);
      int rr = rw + kg * 4 + g, cc = ct * 16 + c15;
      unsigned short h = bf_hi(v);
      tt[0][rr][cc] = h;
      tt[1][rr][cc] = bf_hi(v - bf_to_f(h));
    }
  }
  __syncthreads();  // B2: t tile complete (and all mt reads done)

  // ---- phase 3: GEMM2 + stats ----
  bf16x8 a2h[2], a2l[2];
#pragma unroll
  for (int ks = 0; ks < 2; ++ks) {
    a2h[ks] = *(const bf16x8*)&tt[0][rw + c15][ks * 32 + kg * 8];
    a2l[ks] = *(const bf16x8*)&tt[1][rw + c15][ks * 32 + kg * 8];
  }
  const bf16x8* b2h = (const bf16x8*)(lw + 8192);
  const bf16x8* b2l = (const bf16x8*)(lw + 12288);
  float s = 0.f, ss = 0.f;
  {
    f32x4 acc = {0.f, 0.f, 0.f, 0.f};
#pragma unroll
    for (int ks = 0; ks < 2; ++ks) {
      bf16x8 wbh = b2h[(ks * 4 + ct) * 64 + lane];
      bf16x8 wbl = b2l[(ks * 4 + ct) * 64 + lane];
      acc = MFMA(a2l[ks], wbh, acc, 0, 0, 0);
      acc = MFMA(a2h[ks], wbl, acc, 0, 0, 0);
      acc = MFMA(a2h[ks], wbh, acc, 0, 0, 0);
    }
    unsigned short* rp = rb + (size_t)(ct >> 1) * PL + (ct & 1) * 16 + c15;
#pragma unroll
    for (int g = 0; g < 4; ++g) {
      float v = fmaxf(acc[g], 0.f);
      int row = nbase + rw + kg * 4 + g;
      if (row < NN) rp[(size_t)row * 32] = bf_hi(v);
      s += v;  // OOB rows produce exactly 0 (zeroed m rows)
      ss += v * v;
    }
  }
  s += __shfl_xor(s, 16); s += __shfl_xor(s, 32);    // sum over kg -> wave's 16 rows
  ss += __shfl_xor(ss, 16); ss += __shfl_xor(ss, 32);
  float* reds = &mt[0][0];        // reuse mt region: [16][64] + [16][64]
  float* redss = reds + 1024;
  if (kg == 0) {
    reds[wv * 64 + ct * 16 + c15] = s;
    redss[wv * 64 + ct * 16 + c15] = ss;
  }
  __syncthreads();  // B3
  if (t < 64) {
    int ctc = t >> 4;  // this column's tile
    float s2 = 0.f, ss2 = 0.f;
#pragma unroll
    for (int i = 0; i < 4; ++i) {
      s2 += reds[(i * 4 + ctc) * 64 + t];
      ss2 += redss[(i * 4 + ctc) * 64 + t];
    }
    int cp = (blockIdx.x & (NCOPY - 1)) * 128;
    atomicAdd(&part_out[cp + t], s2);
    atomicAdd(&part_out[cp + 64 + t], ss2);
  }
}

// ---------------- final BN apply (plane-layout bf16 in, fp32 out) ----------------

__global__ __launch_bounds__(256) void k_apply(const unsigned short* __restrict__ rb,
                                               const float* __restrict__ part,
                                               const float* __restrict__ gamma,
                                               const float* __restrict__ beta,
                                               float* __restrict__ out) {
  __shared__ float sc[64], sh[64];
  int t = threadIdx.x;
  if (t < 64) {
    float s = 0.f, ss = 0.f;
#pragma unroll
    for (int c = 0; c < NCOPY; ++c) { s += part[c * 128 + t]; ss += part[c * 128 + 64 + t]; }
    float invn = 1.f / (float)NN;
    float mu = s * invn;
    float var = fmaxf(ss * invn - mu * mu, 0.f);
    float inv = rsqrtf(var + BN_EPS);
    float scale = gamma[t] * inv;
    sc[t] = scale;
    sh[t] = beta[t] - mu * scale;
  }
  __syncthreads();
  int i = blockIdx.x * 256 + t;  // uint2 group index, NN*16 total
  if (i < NN * 16) {
    int node = i >> 4;
    int q = i & 15;
    int plane = q >> 3;
    int off = (q & 7) * 4;
    int c0 = plane * 32 + off;
    uint2 u = *(const uint2*)(rb + (size_t)plane * PL + (size_t)node * 32 + off);
    float4 o;
    o.x = bf_lo_f(u.x) * sc[c0 + 0] + sh[c0 + 0];
    o.y = bf_hi_f(u.x) * sc[c0 + 1] + sh[c0 + 1];
    o.z = bf_lo_f(u.y) * sc[c0 + 2] + sh[c0 + 2];
    o.w = bf_hi_f(u.y) * sc[c0 + 3] + sh[c0 + 3];
    *(float4*)(out + (size_t)node * 64 + c0) = o;
  }
}

// ---------------- launch ----------------

extern "C" void kernel_launch(void* const* d_in, const int* in_sizes, int n_in,
                              void* d_out, int out_size, void* d_ws, size_t ws_size,
                              hipStream_t stream) {
  (void)in_sizes; (void)n_in; (void)out_size; (void)ws_size;
  const float* x      = (const float*)d_in[0];
  const int*   ei     = (const int*)d_in[1];
  const float* Wt     = (const float*)d_in[2];
  const float* bt     = (const float*)d_in[3];
  const float* gt     = (const float*)d_in[4];
  const float* bet    = (const float*)d_in[5];
  const float* Ws1    = (const float*)d_in[6];
  const float* Ws2    = (const float*)d_in[7];
  const float* gammas = (const float*)d_in[8];
  const float* betas  = (const float*)d_in[9];

  const int* esrc = ei;
  const int* edst = ei + NE;

  unsigned short* wp       = (unsigned short*)d_ws;        // 65536 ushorts (128 KB)
  unsigned short* bfA      = wp + 65536;                   // 2 planes x NN*32
  unsigned short* bfB      = bfA + 2 * PL;                 // 2 planes x NN*32
  unsigned short* eb16     = bfB + 2 * PL;                 // NE
  int*            pairs    = (int*)(eb16 + NE);            // NB*CAP (fixed stride)
  int*            rowptr   = pairs + NB * CAP;             // NN+1
  int*            ccur     = rowptr + NN + 1;              // NB
  float*          partials = (float*)(ccur + NB);          // 4 x SEG

  const unsigned short* wth = wp;
  const unsigned short* wtl = wp + 8192;

  const int GB = (NN + 63) / 64;  // 782

  // prep (zero + weight planes) + CSR build
  k_prep<<<128, 256, 0, stream>>>(Wt, Ws1, Ws2, wp, ccur, partials);
  k_part<<<(NE + EPB - 1) / EPB, 256, 0, stream>>>(esrc, edst, ccur, pairs);
  k_sub<<<NB, 256, 0, stream>>>(pairs, ccur, rowptr, eb16);

  // input transform -> bfA (stats seg0)
  k_in<<<GB, 256, 0, stream>>>(x, wth, wtl, bt, bfA, partials);

  // fused layers
  for (int l = 0; l < 3; ++l) {
    const unsigned short* zin = (l & 1) ? bfB : bfA;
    unsigned short* rout = (l & 1) ? bfA : bfB;
    const float* g = (l == 0) ? gt : gammas + (l - 1) * NH;
    const float* b = (l == 0) ? bet : betas + (l - 1) * NH;
    const unsigned short* wl = wp + 16384 + l * 16384;
    k_layer<<<GB, 1024, 0, stream>>>(zin, eb16, rowptr, partials + l * SEG, g, b, wl, rout,
                                     partials + (l + 1) * SEG);
  }

  // final BN apply -> d_out
  k_apply<<<(NN * 16 + 255) / 256, 256, 0, stream>>>(bfB, partials + 3 * SEG,
                                                     gammas + 2 * NH, betas + 2 * NH,
                                                     (float*)d_out);
}

// Round 14
// 164.659 us; speedup vs baseline: 1.2490x; 1.2490x over previous
//
#include <hip/hip_runtime.h>

#define NN 50000
#define NE 800000
#define NF 128
#define NH 64
#define BN_EPS 1e-5f
#define NB 196       // ceil(NN/256) coarse buckets (256 nodes each)
#define EPB 2048     // edges per k_part block
#define CAP 5120     // fixed per-bucket capacity (mean 4082, +16 sigma)
#define NCOPY 16
#define SEG (NCOPY * 128)

typedef __bf16 bf16x8 __attribute__((ext_vector_type(8)));
typedef float f32x4 __attribute__((ext_vector_type(4)));
#define MFMA __builtin_amdgcn_mfma_f32_16x16x32_bf16

__device__ inline unsigned short bf_hi(float f) {
  unsigned u = __float_as_uint(f);
  unsigned r = u + 0x7FFFu + ((u >> 16) & 1u);
  return (unsigned short)(r >> 16);
}
__device__ inline float bf_to_f(unsigned short s) {
  return __uint_as_float(((unsigned)s) << 16);
}
__device__ inline float bf_lo_f(unsigned u) { return __uint_as_float(u << 16); }
__device__ inline float bf_hi_f(unsigned u) { return __uint_as_float(u & 0xFFFF0000u); }

union BF8 { bf16x8 v; unsigned short s[8]; };

// Build hi/lo bf16x8 fragments from 8 consecutive fp32.
__device__ inline void make_ab(const float* p, bool valid, bf16x8& hi, bf16x8& lo) {
  BF8 H, L;
  if (valid) {
    float4 f0 = *(const float4*)p;
    float4 f1 = *(const float4*)(p + 4);
    float ff[8] = {f0.x, f0.y, f0.z, f0.w, f1.x, f1.y, f1.z, f1.w};
#pragma unroll
    for (int e = 0; e < 8; ++e) {
      unsigned short h = bf_hi(ff[e]);
      H.s[e] = h;
      L.s[e] = bf_hi(ff[e] - bf_to_f(h));
    }
  } else {
#pragma unroll
    for (int e = 0; e < 8; ++e) { H.s[e] = 0; L.s[e] = 0; }
  }
  hi = H.v; lo = L.v;
}

// fragment-layout offset for a [K][64] matrix
__device__ inline int frag_off(int k, int c) {
  return ((k >> 5) * 4 + (c >> 4)) * 512 + (((k >> 3) & 3) * 16 + (c & 15)) * 8 + (k & 7);
}

// ---- prep: zero counters/partials + convert all weights to hi/lo fragment planes ----
// wp layout (ushorts): [0,8192) Wt_hi | [8192,16384) Wt_lo |
//   per layer l: 16384 + l*16384 + {0:W1h, 4096:W1l, 8192:W2h, 12288:W2l}

__global__ __launch_bounds__(256) void k_prep(const float* __restrict__ Wt,
                                              const float* __restrict__ Ws1,
                                              const float* __restrict__ Ws2,
                                              unsigned short* __restrict__ wp,
                                              int* __restrict__ ccur,
                                              float* __restrict__ partials) {
  int idx = blockIdx.x * 256 + threadIdx.x;  // 0..32767
  if (idx < NB) ccur[idx] = 0;
  if (idx < 4 * SEG) partials[idx] = 0.f;
  if (idx < 8192) {
    int k = idx >> 6, c = idx & 63;
    float f = Wt[idx];
    int off = frag_off(k, c);
    unsigned short h = bf_hi(f);
    wp[off] = h;
    wp[8192 + off] = bf_hi(f - bf_to_f(h));
  } else {
    int rem = idx - 8192;       // 0..24575
    int l = rem >> 13;          // layer 0..2
    int r2 = rem & 8191;
    int mat = r2 >> 12;         // 0=W1, 1=W2
    int e = r2 & 4095;
    int k = e >> 6, c = e & 63;
    float f = (mat ? Ws2 : Ws1)[l * 4096 + e];
    int off = frag_off(k, c);
    unsigned short* base = wp + 16384 + l * 16384 + mat * 8192;
    unsigned short h = bf_hi(f);
    base[off] = h;
    base[off + 4096] = bf_hi(f - bf_to_f(h));
  }
}

// -------- phase 1: partition packed records into FIXED-STRIDE coarse buckets --------
// record = (dst & 255) << 16 | src. Bucket b owns pairs[b*CAP .. b*CAP+CAP).

__global__ __launch_bounds__(256) void k_part(const int* __restrict__ src,
                                              const int* __restrict__ dst,
                                              int* __restrict__ ccur,
                                              int* __restrict__ pairs) {
  __shared__ int lh[NB];
  __shared__ int gb[NB];
  __shared__ int lc[NB];
  __shared__ int ls[256];
  __shared__ int lp[EPB];
  __shared__ int gx[EPB];
  int t = threadIdx.x;
  for (int i = t; i < NB; i += 256) lh[i] = 0;
  __syncthreads();
  int e0 = blockIdx.x * EPB;
  int nloc = NE - e0; if (nloc > EPB) nloc = EPB;
#pragma unroll
  for (int i = 0; i < EPB / 256; ++i) {
    int e = e0 + i * 256 + t;
    if (e < NE) atomicAdd(&lh[dst[e] >> 8], 1);
  }
  __syncthreads();
  // scan own counts -> local exclusive base
  int v = (t < NB) ? lh[t] : 0;
  ls[t] = v;
  __syncthreads();
  for (int off = 1; off < 256; off <<= 1) {
    int u = (t >= off) ? ls[t - off] : 0;
    __syncthreads();
    ls[t] += u;
    __syncthreads();
  }
  int lbase = ls[t] - v;
  int gbase = 0;
  if (t < NB && v > 0) gbase = t * CAP + atomicAdd(&ccur[t], v);
  if (t < NB) { lh[t] = lbase; gb[t] = gbase; lc[t] = 0; }
  __syncthreads();
#pragma unroll
  for (int i = 0; i < EPB / 256; ++i) {
    int e = e0 + i * 256 + t;
    if (e < NE) {
      int d = dst[e], s = src[e];
      int b = d >> 8;
      int lpos = lh[b] + atomicAdd(&lc[b], 1);
      lp[lpos] = ((d & 255) << 16) | s;
      gx[lpos] = gb[b] - lh[b];
    }
  }
  __syncthreads();
  for (int i = t; i < nloc; i += 256) pairs[gx[i] + i] = lp[i];
}

// ---- phase 2: exact sort within bucket -> rowptr + ebuf(ushort); offsets from ccur scan ----

__global__ __launch_bounds__(256) void k_sub(const int* __restrict__ pairs,
                                             const int* __restrict__ ccur,
                                             int* __restrict__ rowptr,
                                             unsigned short* __restrict__ ebuf) {
  __shared__ int lh[256];
  __shared__ int lsc[256];
  __shared__ int lc2[256];
  __shared__ unsigned short ssrc[CAP];
  int t = threadIdx.x;
  int b = blockIdx.x;
  // scan bucket counts -> global CSR offsets
  int gv = (t < NB) ? ccur[t] : 0;
  lsc[t] = gv;
  __syncthreads();
  for (int off = 1; off < 256; off <<= 1) {
    int u = (t >= off) ? lsc[t - off] : 0;
    __syncthreads();
    lsc[t] += u;
    __syncthreads();
  }
  int beg = (b == 0) ? 0 : lsc[b - 1];
  int n = lsc[b] - beg;
  __syncthreads();
  const int* bp = pairs + b * CAP;
  lh[t] = 0;
  lc2[t] = 0;
  __syncthreads();
  for (int i = t; i < n; i += 256) atomicAdd(&lh[(bp[i] >> 16) & 255], 1);
  __syncthreads();
  int v = lh[t];
  lsc[t] = v;
  __syncthreads();
  for (int off = 1; off < 256; off <<= 1) {
    int u = (t >= off) ? lsc[t - off] : 0;
    __syncthreads();
    lsc[t] += u;
    __syncthreads();
  }
  int excl = lsc[t] - v;
  int node = b * 256 + t;
  if (node <= NN) rowptr[node] = beg + excl;
  for (int i = t; i < n; i += 256) {
    int p = bp[i];
    int ln = (p >> 16) & 255;
    int lpos = (lsc[ln] - lh[ln]) + atomicAdd(&lc2[ln], 1);
    if (lpos < CAP) ssrc[lpos] = (unsigned short)(p & 0xFFFF);
  }
  __syncthreads();
  for (int i = t; i < n; i += 256) ebuf[beg + i] = ssrc[i];
}

// ------- input transform (MFMA; pre-converted weights copied global->LDS) -------

__global__ __launch_bounds__(256) void k_in(const float* __restrict__ x,
                                            const unsigned short* __restrict__ wth,
                                            const unsigned short* __restrict__ wtl,
                                            const float* __restrict__ bt,
                                            unsigned short* __restrict__ zb,
                                            float* __restrict__ part_out) {
  __shared__ unsigned short lwh[8192], lwl[8192];  // 32 KB
  int t = threadIdx.x;
  {
    const uint4* gh = (const uint4*)wth;
    const uint4* gl = (const uint4*)wtl;
    uint4* dh = (uint4*)lwh;
    uint4* dl = (uint4*)lwl;
#pragma unroll
    for (int i = 0; i < 4; ++i) {
      dh[t + i * 256] = gh[t + i * 256];
      dl[t + i * 256] = gl[t + i * 256];
    }
  }
  int wv = t >> 6, lane = t & 63;
  int c15 = lane & 15, kg = lane >> 4;
  int n0 = blockIdx.x * 64 + wv * 16;
  int arow = n0 + c15;
  bool valid = arow < NN;

  bf16x8 ah[4], al[4];
  const float* ap = x + (size_t)(valid ? arow : 0) * NF + kg * 8;
#pragma unroll
  for (int ks = 0; ks < 4; ++ks) make_ab(ap + ks * 32, valid, ah[ks], al[ks]);
  __syncthreads();

  const bf16x8* bh = (const bf16x8*)lwh;
  const bf16x8* bl = (const bf16x8*)lwl;
  float sAcc[4], ssAcc[4];
#pragma unroll
  for (int ct = 0; ct < 4; ++ct) {
    f32x4 acc = {0.f, 0.f, 0.f, 0.f};
#pragma unroll
    for (int ks = 0; ks < 4; ++ks) {
      bf16x8 wbh = bh[(ks * 4 + ct) * 64 + lane];
      bf16x8 wbl = bl[(ks * 4 + ct) * 64 + lane];
      acc = MFMA(al[ks], wbh, acc, 0, 0, 0);
      acc = MFMA(ah[ks], wbl, acc, 0, 0, 0);
      acc = MFMA(ah[ks], wbh, acc, 0, 0, 0);
    }
    float b = bt[ct * 16 + c15];
    float s = 0.f, ss = 0.f;
#pragma unroll
    for (int g = 0; g < 4; ++g) {
      int row = n0 + kg * 4 + g;
      float v = acc[g] + b;
      if (row < NN) {
        zb[(size_t)row * NH + ct * 16 + c15] = bf_hi(v);
        s += v;
        ss += v * v;
      }
    }
    sAcc[ct] = s;
    ssAcc[ct] = ss;
  }
#pragma unroll
  for (int ct = 0; ct < 4; ++ct) {
    float s = sAcc[ct];
    s += __shfl_xor(s, 16); s += __shfl_xor(s, 32);
    float ss = ssAcc[ct];
    ss += __shfl_xor(ss, 16); ss += __shfl_xor(ss, 32);
    if (kg == 0) {
      int cp = ((blockIdx.x * 4 + wv) & (NCOPY - 1)) * 128;
      atomicAdd(&part_out[cp + ct * 16 + c15], s);
      atomicAdd(&part_out[cp + 64 + ct * 16 + c15], ss);
    }
  }
}

// ======== fused layer: gather+BN (16 waves x 4 nodes) -> LDS m tile -> MFMA MLP ========
// rb = bf16( relu( relu( BN(agg) @ W1 ) @ W2 ) ), stats -> part_out

__global__ __launch_bounds__(1024) void k_layer(const unsigned short* __restrict__ zb,
                                                const unsigned short* __restrict__ ebuf,
                                                const int* __restrict__ rowptr,
                                                const float* __restrict__ part_in,
                                                const float* __restrict__ gamma,
                                                const float* __restrict__ beta,
                                                const unsigned short* __restrict__ wl,
                                                unsigned short* __restrict__ rb,
                                                float* __restrict__ part_out) {
  __shared__ unsigned short lw[16384];       // W1h|W1l|W2h|W2l (32 KB)
  __shared__ float mt[64][68];               // m tile fp32; reused for stats
  __shared__ unsigned short tt[2][64][72];   // t tile hi/lo
  __shared__ float sc[64], sh[64];
  int t = threadIdx.x;
  {  // stage weights (plain vector copy)
    const uint4* g = (const uint4*)wl;
    uint4* d = (uint4*)lw;
    d[t] = g[t];
    d[t + 1024] = g[t + 1024];
  }
  if (t < 64) {
    float s = 0.f, ss = 0.f;
#pragma unroll
    for (int c = 0; c < NCOPY; ++c) { s += part_in[c * 128 + t]; ss += part_in[c * 128 + 64 + t]; }
    float invn = 1.f / (float)NN;
    float mu = s * invn;
    float var = fmaxf(ss * invn - mu * mu, 0.f);
    float inv = rsqrtf(var + BN_EPS);
    float scale = gamma[t] * inv;
    sc[t] = scale;
    sh[t] = beta[t] - mu * scale;
  }
  __syncthreads();  // B0: weights + sc/sh ready

  int wv = t >> 6, lane = t & 63;
  int slot = lane >> 4;   // edge slot 0..3
  int cg = lane & 15;     // channel group (4 ch each)
  int nbase = blockIdx.x * 64;

  // ---- phase 1: gather 4 nodes per wave (16-edge main loop, 4 loads in flight) ----
  for (int i = 0; i < 4; ++i) {
    int nl = wv * 4 + i;
    int node = nbase + nl;
    if (node >= NN) {
      if (slot == 0) *(float4*)&mt[nl][cg * 4] = make_float4(0.f, 0.f, 0.f, 0.f);
      continue;  // wave-uniform
    }
    int beg = rowptr[node], end = rowptr[node + 1];
    float a0 = 0.f, a1 = 0.f, a2 = 0.f, a3 = 0.f;
    if (slot == 0) {  // self term (bf16)
      uint2 u = *(const uint2*)(zb + (size_t)node * NH + cg * 4);
      a0 = bf_lo_f(u.x); a1 = bf_hi_f(u.x); a2 = bf_lo_f(u.y); a3 = bf_hi_f(u.y);
    }
    int j = beg + slot;
    for (; j + 12 < end; j += 16) {  // 16 edges/wave-iter, 4 rows in flight per lane
      int s0 = ebuf[j];
      int s1 = ebuf[j + 4];
      int s2 = ebuf[j + 8];
      int s3 = ebuf[j + 12];
      uint2 u0 = *(const uint2*)(zb + (size_t)s0 * NH + cg * 4);
      uint2 u1 = *(const uint2*)(zb + (size_t)s1 * NH + cg * 4);
      uint2 u2 = *(const uint2*)(zb + (size_t)s2 * NH + cg * 4);
      uint2 u3 = *(const uint2*)(zb + (size_t)s3 * NH + cg * 4);
      a0 += (bf_lo_f(u0.x) + bf_lo_f(u1.x)) + (bf_lo_f(u2.x) + bf_lo_f(u3.x));
      a1 += (bf_hi_f(u0.x) + bf_hi_f(u1.x)) + (bf_hi_f(u2.x) + bf_hi_f(u3.x));
      a2 += (bf_lo_f(u0.y) + bf_lo_f(u1.y)) + (bf_lo_f(u2.y) + bf_lo_f(u3.y));
      a3 += (bf_hi_f(u0.y) + bf_hi_f(u1.y)) + (bf_hi_f(u2.y) + bf_hi_f(u3.y));
    }
    for (; j + 4 < end; j += 8) {  // 8-edge mid loop
      int s0 = ebuf[j];
      int s1 = ebuf[j + 4];
      uint2 u0 = *(const uint2*)(zb + (size_t)s0 * NH + cg * 4);
      uint2 u1 = *(const uint2*)(zb + (size_t)s1 * NH + cg * 4);
      a0 += bf_lo_f(u0.x) + bf_lo_f(u1.x);
      a1 += bf_hi_f(u0.x) + bf_hi_f(u1.x);
      a2 += bf_lo_f(u0.y) + bf_lo_f(u1.y);
      a3 += bf_hi_f(u0.y) + bf_hi_f(u1.y);
    }
    for (; j < end; j += 4) {
      int s0 = ebuf[j];
      uint2 u0 = *(const uint2*)(zb + (size_t)s0 * NH + cg * 4);
      a0 += bf_lo_f(u0.x);
      a1 += bf_hi_f(u0.x);
      a2 += bf_lo_f(u0.y);
      a3 += bf_hi_f(u0.y);
    }
    a0 += __shfl_xor(a0, 16); a0 += __shfl_xor(a0, 32);
    a1 += __shfl_xor(a1, 16); a1 += __shfl_xor(a1, 32);
    a2 += __shfl_xor(a2, 16); a2 += __shfl_xor(a2, 32);
    a3 += __shfl_xor(a3, 16); a3 += __shfl_xor(a3, 32);
    if (slot == 0) {
      float deg1 = (float)(end - beg + 1);
      int c0 = cg * 4;
      float4 o;
      o.x = sc[c0 + 0] * a0 + deg1 * sh[c0 + 0];
      o.y = sc[c0 + 1] * a1 + deg1 * sh[c0 + 1];
      o.z = sc[c0 + 2] * a2 + deg1 * sh[c0 + 2];
      o.w = sc[c0 + 3] * a3 + deg1 * sh[c0 + 3];
      *(float4*)&mt[nl][c0] = o;
    }
  }
  __syncthreads();  // B1: m tile complete

  // ---- phase 2: GEMM1 (16 waves = 4 row-blocks x 4 col-tiles) ----
  int rw = (wv >> 2) * 16;  // row offset of this wave's 16x16 tile
  int ct = wv & 3;          // col tile
  int c15 = lane & 15, kg = lane >> 4;

  bf16x8 ah[2], al[2];
#pragma unroll
  for (int ks = 0; ks < 2; ++ks) make_ab(&mt[rw + c15][ks * 32 + kg * 8], true, ah[ks], al[ks]);

  const bf16x8* b1h = (const bf16x8*)lw;
  const bf16x8* b1l = (const bf16x8*)(lw + 4096);
  {
    f32x4 acc = {0.f, 0.f, 0.f, 0.f};
#pragma unroll
    for (int ks = 0; ks < 2; ++ks) {
      bf16x8 wbh = b1h[(ks * 4 + ct) * 64 + lane];
      bf16x8 wbl = b1l[(ks * 4 + ct) * 64 + lane];
      acc = MFMA(al[ks], wbh, acc, 0, 0, 0);
      acc = MFMA(ah[ks], wbl, acc, 0, 0, 0);
      acc = MFMA(ah[ks], wbh, acc, 0, 0, 0);
    }
#pragma unroll
    for (int g = 0; g < 4; ++g) {
      float v = fmaxf(acc[g], 0.f);
      int rr = rw + kg * 4 + g, cc = ct * 16 + c15;
      unsigned short h = bf_hi(v);
      tt[0][rr][cc] = h;
      tt[1][rr][cc] = bf_hi(v - bf_to_f(h));
    }
  }
  __syncthreads();  // B2: t tile complete (and all mt reads done)

  // ---- phase 3: GEMM2 + stats ----
  bf16x8 a2h[2], a2l[2];
#pragma unroll
  for (int ks = 0; ks < 2; ++ks) {
    a2h[ks] = *(const bf16x8*)&tt[0][rw + c15][ks * 32 + kg * 8];
    a2l[ks] = *(const bf16x8*)&tt[1][rw + c15][ks * 32 + kg * 8];
  }
  const bf16x8* b2h = (const bf16x8*)(lw + 8192);
  const bf16x8* b2l = (const bf16x8*)(lw + 12288);
  float s = 0.f, ss = 0.f;
  {
    f32x4 acc = {0.f, 0.f, 0.f, 0.f};
#pragma unroll
    for (int ks = 0; ks < 2; ++ks) {
      bf16x8 wbh = b2h[(ks * 4 + ct) * 64 + lane];
      bf16x8 wbl = b2l[(ks * 4 + ct) * 64 + lane];
      acc = MFMA(a2l[ks], wbh, acc, 0, 0, 0);
      acc = MFMA(a2h[ks], wbl, acc, 0, 0, 0);
      acc = MFMA(a2h[ks], wbh, acc, 0, 0, 0);
    }
#pragma unroll
    for (int g = 0; g < 4; ++g) {
      float v = fmaxf(acc[g], 0.f);
      int row = nbase + rw + kg * 4 + g;
      if (row < NN) rb[(size_t)row * NH + ct * 16 + c15] = bf_hi(v);
      s += v;  // OOB rows produce exactly 0 (zeroed m rows)
      ss += v * v;
    }
  }
  s += __shfl_xor(s, 16); s += __shfl_xor(s, 32);    // sum over kg -> wave's 16 rows
  ss += __shfl_xor(ss, 16); ss += __shfl_xor(ss, 32);
  float* reds = &mt[0][0];        // reuse mt region: [16][64] + [16][64]
  float* redss = reds + 1024;
  if (kg == 0) {
    reds[wv * 64 + ct * 16 + c15] = s;
    redss[wv * 64 + ct * 16 + c15] = ss;
  }
  __syncthreads();  // B3
  if (t < 64) {
    int ctc = t >> 4;  // this column's tile
    float s2 = 0.f, ss2 = 0.f;
#pragma unroll
    for (int i = 0; i < 4; ++i) {
      s2 += reds[(i * 4 + ctc) * 64 + t];
      ss2 += redss[(i * 4 + ctc) * 64 + t];
    }
    int cp = (blockIdx.x & (NCOPY - 1)) * 128;
    atomicAdd(&part_out[cp + t], s2);
    atomicAdd(&part_out[cp + 64 + t], ss2);
  }
}

// ---------------- final BN apply (bf16 in, fp32 out) ----------------

__global__ __launch_bounds__(256) void k_apply(const unsigned short* __restrict__ rb,
                                               const float* __restrict__ part,
                                               const float* __restrict__ gamma,
                                               const float* __restrict__ beta,
                                               float* __restrict__ out) {
  __shared__ float sc[64], sh[64];
  int t = threadIdx.x;
  if (t < 64) {
    float s = 0.f, ss = 0.f;
#pragma unroll
    for (int c = 0; c < NCOPY; ++c) { s += part[c * 128 + t]; ss += part[c * 128 + 64 + t]; }
    float invn = 1.f / (float)NN;
    float mu = s * invn;
    float var = fmaxf(ss * invn - mu * mu, 0.f);
    float inv = rsqrtf(var + BN_EPS);
    float scale = gamma[t] * inv;
    sc[t] = scale;
    sh[t] = beta[t] - mu * scale;
  }
  __syncthreads();
  int i = blockIdx.x * 256 + t;  // 4-channel group index
  if (i < NN * (NH / 4)) {
    int c0 = (i * 4) & 63;
    uint2 u = ((const uint2*)rb)[i];
    float4 o;
    o.x = bf_lo_f(u.x) * sc[c0 + 0] + sh[c0 + 0];
    o.y = bf_hi_f(u.x) * sc[c0 + 1] + sh[c0 + 1];
    o.z = bf_lo_f(u.y) * sc[c0 + 2] + sh[c0 + 2];
    o.w = bf_hi_f(u.y) * sc[c0 + 3] + sh[c0 + 3];
    ((float4*)out)[i] = o;
  }
}

// ---------------- launch ----------------

extern "C" void kernel_launch(void* const* d_in, const int* in_sizes, int n_in,
                              void* d_out, int out_size, void* d_ws, size_t ws_size,
                              hipStream_t stream) {
  (void)in_sizes; (void)n_in; (void)out_size; (void)ws_size;
  const float* x      = (const float*)d_in[0];
  const int*   ei     = (const int*)d_in[1];
  const float* Wt     = (const float*)d_in[2];
  const float* bt     = (const float*)d_in[3];
  const float* gt     = (const float*)d_in[4];
  const float* bet    = (const float*)d_in[5];
  const float* Ws1    = (const float*)d_in[6];
  const float* Ws2    = (const float*)d_in[7];
  const float* gammas = (const float*)d_in[8];
  const float* betas  = (const float*)d_in[9];

  const int* esrc = ei;
  const int* edst = ei + NE;

  unsigned short* wp       = (unsigned short*)d_ws;        // 65536 ushorts (128 KB)
  unsigned short* bfA      = wp + 65536;                   // NN*NH
  unsigned short* bfB      = bfA + (size_t)NN * NH;        // NN*NH
  unsigned short* eb16     = bfB + (size_t)NN * NH;        // NE
  int*            pairs    = (int*)(eb16 + NE);            // NB*CAP (fixed stride)
  int*            rowptr   = pairs + NB * CAP;             // NN+1
  int*            ccur     = rowptr + NN + 1;              // NB
  float*          partials = (float*)(ccur + NB);          // 4 x SEG

  const unsigned short* wth = wp;
  const unsigned short* wtl = wp + 8192;

  const int GB = (NN + 63) / 64;  // 782

  // prep (zero + weight planes) + CSR build (no global histogram pass)
  k_prep<<<128, 256, 0, stream>>>(Wt, Ws1, Ws2, wp, ccur, partials);
  k_part<<<(NE + EPB - 1) / EPB, 256, 0, stream>>>(esrc, edst, ccur, pairs);
  k_sub<<<NB, 256, 0, stream>>>(pairs, ccur, rowptr, eb16);

  // input transform -> bfA (stats seg0)
  k_in<<<GB, 256, 0, stream>>>(x, wth, wtl, bt, bfA, partials);

  // fused layers
  for (int l = 0; l < 3; ++l) {
    const unsigned short* zin = (l & 1) ? bfB : bfA;
    unsigned short* rout = (l & 1) ? bfA : bfB;
    const float* g = (l == 0) ? gt : gammas + (l - 1) * NH;
    const float* b = (l == 0) ? bet : betas + (l - 1) * NH;
    const unsigned short* wl = wp + 16384 + l * 16384;
    k_layer<<<GB, 1024, 0, stream>>>(zin, eb16, rowptr, partials + l * SEG, g, b, wl, rout,
                                     partials + (l + 1) * SEG);
  }

  // final BN apply -> d_out
  k_apply<<<(NN * (NH / 4) + 255) / 256, 256, 0, stream>>>(bfB, partials + 3 * SEG,
                                                           gammas + 2 * NH, betas + 2 * NH,
                                                           (float*)d_out);
}